// Round 8
// baseline (3427.418 us; speedup 1.0000x reference)
//
#include <hip/hip_runtime.h>
#include <hip/hip_bf16.h>
#include <math.h>

#define BSZ   64
#define LSEQ  512
#define EDIM  300
#define HDIM  256
#define TLEN  1023
#define PROJW 512
#define GW    1280

#define NROW  8         // rows per block (row-group)
#define NHID  8         // gate-columns per block
#define NRG   8
#define NBLK  256
#define SLOTS 2

#define PROJ_N   (BSZ*LSEQ*PROJW)          // 16,777,216 dwords
#define STACKF   PROJ_N                    // pair region base (dwords)
#define PAIRB    (STACKF/2)                // pair region base (8B pair units)
#define PAIR_CNT (2*BSZ*SLOTS*HDIM)        // 65,536 pairs = 512 KB

#define NODEBIT 0x80000000u
#define SENT    0xFFFFFFFFu
#define LROW    264                        // LDS row stride (dwords)
#define HRO     (NROW*LROW + 4)            // hr-buffer offset

// ---------------- Kernel 1: proj = sentence @ W_word + b_word ----------------
__global__ void __launch_bounds__(256)
proj_gemm(const float* __restrict__ A, const float* __restrict__ W,
          const float* __restrict__ bias, float* __restrict__ out) {
    __shared__ float As[8][65];
    __shared__ float Bs[8][64];
    const int tid = threadIdx.x;
    const int tx = tid & 15, ty = tid >> 4;
    const int bm = blockIdx.y, bn = blockIdx.x;

    float acc[4][4] = {};
    const int e  = tid * 2;
    const int ar = e >> 3, ac = e & 7;
    const int br = e >> 6, bc = e & 63;

    for (int k0 = 0; k0 < EDIM; k0 += 8) {
        __syncthreads();
        {
            const float* Ap = A + (size_t)(bm * 64 + ar) * EDIM;
            int gk = k0 + ac;
            As[ac][ar]     = (gk     < EDIM) ? Ap[gk]     : 0.f;
            As[ac + 1][ar] = (gk + 1 < EDIM) ? Ap[gk + 1] : 0.f;
            int gkb = k0 + br;
            float w0 = 0.f, w1 = 0.f;
            if (gkb < EDIM) {
                const float* Wp = W + (size_t)gkb * PROJW + bn * 64;
                w0 = Wp[bc]; w1 = Wp[bc + 1];
            }
            Bs[br][bc] = w0; Bs[br][bc + 1] = w1;
        }
        __syncthreads();
        #pragma unroll
        for (int kk = 0; kk < 8; ++kk) {
            float a[4], b[4];
            #pragma unroll
            for (int i = 0; i < 4; ++i) a[i] = As[kk][ty * 4 + i];
            #pragma unroll
            for (int j = 0; j < 4; ++j) b[j] = Bs[kk][tx * 4 + j];
            #pragma unroll
            for (int i = 0; i < 4; ++i)
                #pragma unroll
                for (int j = 0; j < 4; ++j)
                    acc[i][j] += a[i] * b[j];
        }
    }
    #pragma unroll
    for (int i = 0; i < 4; ++i) {
        const int row  = bm * 64 + ty * 4 + i;
        const int col0 = bn * 64 + tx * 4;
        float* op = out + (size_t)row * PROJW + col0;
        #pragma unroll
        for (int j = 0; j < 4; ++j) op[j] = acc[i][j] + bias[col0 + j];
    }
}

// ------------- helpers -------------------------------------------------------
__device__ __forceinline__ int qswz(int Q, int row) {
    return Q ^ row ^ ((Q >> 3) & 7);
}

// ------------- Kernel 2: cooperative scan, epoch dataflow, fused finalize ----
__global__ void __launch_bounds__(256, 1)
scan_coop(const int* __restrict__ trans,
          const float* __restrict__ Wl, const float* __restrict__ Wr,
          const float* __restrict__ bred,
          float* __restrict__ ws, float* __restrict__ out) {
    __shared__ __align__(16) float hbuf[HRO + NROW * LROW];   // hl | pad | hr
    __shared__ float    cstk[2 * SLOTS * NROW * NHID];        // private cell stack (1KB)
    __shared__ unsigned tbits[NROW][32];
    __shared__ unsigned fbits[32];
    __shared__ short    tg[NROW][SLOTS];
    __shared__ unsigned eps[NROW][SLOTS];
    __shared__ unsigned d_hl[NROW], d_hr[NROW], d_wr[NROW];
    __shared__ unsigned e_hl[NROW], e_hr[NROW];
    __shared__ unsigned c_l[NROW], c_r[NROW], cw[NROW];
    __shared__ unsigned d_oh[NROW], e_oh[NROW];
    __shared__ int      isred[NROW];

    const int tid   = threadIdx.x;
    // XCD-local mapping: blockIdx % 8 = XCD -> one row-group per XCD.
    const int rg    = blockIdx.x & 7;      // row-group
    const int cs    = blockIdx.x >> 3;     // col-slice
    const int rbase = rg * NROW;
    const int n0    = cs * NHID;

    const int srow = tid >> 5, sc = tid & 31;   // staging map
    const int colq = tid >> 5;                  // gemm: gate-col (wave-group)
    const int m    = (tid >> 4) & 1;            // gemm: matrix (0=hl/Wl, 1=hr/Wr)
    const int w16  = tid & 15;                  // gemm: k-segment (4 quads = 16 k)
    const int gn   = n0 + colq;
    const int lane = tid & 63;

    unsigned long long* p64 = (unsigned long long*)ws;

    // ---- weight slice into REGISTERS (once): 20 float4 = 80 VGPR, NO duplication ----
    float4 w[4][5];
    {
        const float* src = m ? Wr : Wl;
        #pragma unroll
        for (int j = 0; j < 4; ++j) {
            const int k0 = (w16 * 4 + j) * 4;
            #pragma unroll
            for (int g = 0; g < 5; ++g) {
                w[j][g].x = src[(size_t)(k0 + 0) * GW + g * HDIM + gn];
                w[j][g].y = src[(size_t)(k0 + 1) * GW + g * HDIM + gn];
                w[j][g].z = src[(size_t)(k0 + 2) * GW + g * HDIM + gn];
                w[j][g].w = src[(size_t)(k0 + 3) * GW + g * HDIM + gn];
            }
        }
    }
    #pragma unroll
    for (int j = 0; j < 4; ++j)
        #pragma unroll
        for (int g = 0; g < 5; ++g)
            asm volatile("" : "+v"(w[j][g].x), "+v"(w[j][g].y),
                              "+v"(w[j][g].z), "+v"(w[j][g].w));

    // ---- transition bitmasks (shift=1) ----
    if (tid < NROW * 32) {
        const int r2 = tid >> 5, wd = tid & 31;
        unsigned bits = 0;
        for (int j = 0; j < 32; ++j) {
            const int t = wd * 32 + j;
            if (t < TLEN && trans[(size_t)(rbase + r2) * TLEN + t] == 3) bits |= (1u << j);
        }
        tbits[r2][wd] = bits;
    }
    if (tid < NROW) {
        tg[tid][0] = -3; tg[tid][1] = -3;
        eps[tid][0] = 0; eps[tid][1] = 0;
        isred[tid] = 0;
    }
    __syncthreads();
    if (tid < 32) {   // rg-local "any reduce at step t" bits
        unsigned fb = 0;
        #pragma unroll
        for (int r2 = 0; r2 < NROW; ++r2) fb |= ~tbits[r2][tid];
        if (tid == 31) fb &= 0x7FFFFFFFu;   // t=1023 invalid
        fbits[tid] = fb;
    }

    float bv[5];
    #pragma unroll
    for (int g = 0; g < 5; ++g) bv[g] = bred[g * HDIM + gn];

    int ptr = 0, bp = 0;       // controller state (thread tid<NROW owns row tid)
    unsigned nbar = 0;
    __syncthreads();

    for (int t = 0; t < TLEN; ++t) {
        const int redstep = (fbits[t >> 5] >> (t & 31)) & 1;
        if (redstep) ++nbar;

        if (tid < NROW) {
            const int r = tid, grow = rbase + r;
            const int is_shift = (tbits[r][t >> 5] >> (t & 31)) & 1;
            if (is_shift) {
                int pos = ptr; if (pos < 0) pos = 0; if (pos > SLOTS - 1) pos = SLOTS - 1;
                tg[r][pos] = (short)min(bp, LSEQ - 1);
                ptr++; bp++;
                isred[r] = 0;
            } else {
                const int i1 = min(max(ptr - 1, 0), SLOTS - 1);
                const int i2 = min(max(ptr - 2, 0), SLOTS - 1);
                const short t1 = tg[r][i1], t2 = tg[r][i2];
                unsigned dl, el = 0, cdl;
                if (t2 >= 0)       { dl = (unsigned)((grow * LSEQ + (int)t2) * PROJW); cdl = dl + HDIM; }
                else if (t2 <= -3) { dl = SENT; cdl = SENT; }
                else { const int par = (t2 == -2);
                       dl = NODEBIT | (unsigned)(PAIRB + ((par * BSZ + grow) * SLOTS + i2) * HDIM);
                       el = eps[r][i2];
                       cdl = NODEBIT | (unsigned)(par * 2 + i2); }
                unsigned dr, er = 0, cdr;
                if (t1 >= 0)       { dr = (unsigned)((grow * LSEQ + (int)t1) * PROJW); cdr = dr + HDIM; }
                else if (t1 <= -3) { dr = SENT; cdr = SENT; }
                else { const int par = (t1 == -2);
                       dr = NODEBIT | (unsigned)(PAIRB + ((par * BSZ + grow) * SLOTS + i1) * HDIM);
                       er = eps[r][i1];
                       cdr = NODEBIT | (unsigned)(par * 2 + i1); }
                d_hl[r] = dl; e_hl[r] = el; c_l[r] = cdl;
                d_hr[r] = dr; e_hr[r] = er; c_r[r] = cdr;
                const int pnew = (t2 == -1) ? 1 : 0;
                d_wr[r] = (unsigned)(PAIRB + ((pnew * BSZ + grow) * SLOTS + i2) * HDIM);
                cw[r]   = (unsigned)(pnew * 2 + i2);
                eps[r][i2] = nbar;
                tg[r][i2] = (short)(pnew ? -2 : -1);
                ptr--;
                isred[r] = 1;
            }
        }
        __syncthreads();

        if (!redstep) continue;

        // ---- word-path c prefetch for finalize lanes (issue early, use late) ----
        float clw = 0.f, crw = 0.f;
        int frow = 0;
        const bool fin = ((lane & 31) < 8);
        if (fin) {
            frow = ((lane & 1) << 2) | (lane & 2) | ((lane & 4) >> 2);
            if (isred[frow]) {
                const unsigned cdl = c_l[frow], cdr = c_r[frow];
                if (cdl != SENT && !(cdl & NODEBIT)) clw = ws[cdl + gn];
                if (cdr != SENT && !(cdr & NODEBIT)) crw = ws[cdr + gn];
            }
        }

        // ---- staging: issue WORD loads first, then node polls, then LDS writes ----
        if (isred[srow]) {
            const unsigned oh0 = d_hl[srow], oh1 = d_hr[srow];
            const unsigned ee0 = e_hl[srow], ee1 = e_hr[srow];
            const bool nd0 = (oh0 != SENT) && (oh0 & NODEBIT);
            const bool nd1 = (oh1 != SENT) && (oh1 & NODEBIT);
            float h0[8], h1[8];

            // phase A: word/zero sources into registers (loads pend under polls)
            if (oh0 == SENT) {
                #pragma unroll
                for (int i = 0; i < 8; ++i) h0[i] = 0.f;
            } else if (!nd0) {
                const float4 a = *(const float4*)(ws + oh0 + sc * 8);
                const float4 b = *(const float4*)(ws + oh0 + sc * 8 + 4);
                h0[0]=a.x; h0[1]=a.y; h0[2]=a.z; h0[3]=a.w;
                h0[4]=b.x; h0[5]=b.y; h0[6]=b.z; h0[7]=b.w;
            }
            if (oh1 == SENT) {
                #pragma unroll
                for (int i = 0; i < 8; ++i) h1[i] = 0.f;
            } else if (!nd1) {
                const float4 a = *(const float4*)(ws + oh1 + sc * 8);
                const float4 b = *(const float4*)(ws + oh1 + sc * 8 + 4);
                h1[0]=a.x; h1[1]=a.y; h1[2]=a.z; h1[3]=a.w;
                h1[4]=b.x; h1[5]=b.y; h1[6]=b.z; h1[7]=b.w;
            }
            // phase B: node polls (epoch-tagged pairs)
            if (nd0) {
                const unsigned pb = (oh0 & ~NODEBIT) + sc * 8;
                unsigned long long v[8];
                for (;;) {
                    #pragma unroll
                    for (int i = 0; i < 8; ++i)
                        v[i] = __hip_atomic_load(p64 + pb + i,
                                 __ATOMIC_RELAXED, __HIP_MEMORY_SCOPE_AGENT);
                    bool ok = true;
                    #pragma unroll
                    for (int i = 0; i < 8; ++i) ok &= ((unsigned)(v[i] >> 32) >= ee0);
                    if (ok) break;
                    __builtin_amdgcn_s_sleep(1);
                }
                #pragma unroll
                for (int i = 0; i < 8; ++i) h0[i] = __uint_as_float((unsigned)v[i]);
            }
            if (nd1) {
                const unsigned pb = (oh1 & ~NODEBIT) + sc * 8;
                unsigned long long v[8];
                for (;;) {
                    #pragma unroll
                    for (int i = 0; i < 8; ++i)
                        v[i] = __hip_atomic_load(p64 + pb + i,
                                 __ATOMIC_RELAXED, __HIP_MEMORY_SCOPE_AGENT);
                    bool ok = true;
                    #pragma unroll
                    for (int i = 0; i < 8; ++i) ok &= ((unsigned)(v[i] >> 32) >= ee1);
                    if (ok) break;
                    __builtin_amdgcn_s_sleep(1);
                }
                #pragma unroll
                for (int i = 0; i < 8; ++i) h1[i] = __uint_as_float((unsigned)v[i]);
            }
            // phase C: LDS writes (swizzled quads)
            *(float4*)&hbuf[srow * LROW + 4 * qswz(2 * sc + 0, srow)] =
                make_float4(h0[0], h0[1], h0[2], h0[3]);
            *(float4*)&hbuf[srow * LROW + 4 * qswz(2 * sc + 1, srow)] =
                make_float4(h0[4], h0[5], h0[6], h0[7]);
            *(float4*)&hbuf[HRO + srow * LROW + 4 * qswz(2 * sc + 0, srow)] =
                make_float4(h1[0], h1[1], h1[2], h1[3]);
            *(float4*)&hbuf[HRO + srow * LROW + 4 * qswz(2 * sc + 1, srow)] =
                make_float4(h1[4], h1[5], h1[6], h1[7]);
        }
        __syncthreads();

        // ---- GEMM: register weights; thread = (colq, m, w16), all 8 rows ----
        float acc[8][5];
        #pragma unroll
        for (int r = 0; r < 8; ++r)
            #pragma unroll
            for (int g = 0; g < 5; ++g) acc[r][g] = 0.f;
        {
            const float* hb = hbuf + m * HRO;
            #pragma unroll
            for (int j = 0; j < 4; ++j) {
                const int kq = w16 * 4 + j;
                #pragma unroll
                for (int r = 0; r < 8; ++r) {
                    const float4 x = *(const float4*)&hb[r * LROW + 4 * qswz(kq, r)];
                    #pragma unroll
                    for (int g = 0; g < 5; ++g)
                        acc[r][g] += x.x * w[j][g].x + x.y * w[j][g].y
                                   + x.z * w[j][g].z + x.w * w[j][g].w;
                }
            }
        }

        // ---- in-wave butterfly reduction (m then k-segments, row-specializing) ----
        #pragma unroll
        for (int r = 0; r < 8; ++r)
            #pragma unroll
            for (int g = 0; g < 5; ++g)
                acc[r][g] += __shfl_xor(acc[r][g], 16);   // sum over m

        float a4[4][5];
        {
            const bool kl = ((lane & 1) == 0);
            #pragma unroll
            for (int r = 0; r < 4; ++r)
                #pragma unroll
                for (int g = 0; g < 5; ++g) {
                    const float lo = acc[r][g], hi = acc[r + 4][g];
                    const float sd = kl ? hi : lo;
                    const float rc = __shfl_xor(sd, 1);
                    a4[r][g] = (kl ? lo : hi) + rc;
                }
        }
        float a2[2][5];
        {
            const bool kl = ((lane & 2) == 0);
            #pragma unroll
            for (int r = 0; r < 2; ++r)
                #pragma unroll
                for (int g = 0; g < 5; ++g) {
                    const float lo = a4[r][g], hi = a4[r + 2][g];
                    const float sd = kl ? hi : lo;
                    const float rc = __shfl_xor(sd, 2);
                    a2[r][g] = (kl ? lo : hi) + rc;
                }
        }
        float a1[5];
        {
            const bool kl = ((lane & 4) == 0);
            #pragma unroll
            for (int g = 0; g < 5; ++g) {
                const float lo = a2[0][g], hi = a2[1][g];
                const float sd = kl ? hi : lo;
                const float rc = __shfl_xor(sd, 4);
                a1[g] = (kl ? lo : hi) + rc;
            }
        }
        #pragma unroll
        for (int g = 0; g < 5; ++g) a1[g] += __shfl_xor(a1[g], 8);

        // ---- fused finalize: lane (lane&31)<8 owns (row=frow, col=gn) ----
        if (fin && isred[frow]) {
            const unsigned cdl = c_l[frow], cdr = c_r[frow];
            const float cl = (cdl == SENT) ? 0.f :
                ((cdl & NODEBIT) ? cstk[((cdl & 3) * NROW + frow) * NHID + colq] : clw);
            const float cr = (cdr == SENT) ? 0.f :
                ((cdr & NODEBIT) ? cstk[((cdr & 3) * NROW + frow) * NHID + colq] : crw);
            const float s0 = a1[0] + bv[0], s1 = a1[1] + bv[1], s2 = a1[2] + bv[2],
                        s3 = a1[3] + bv[3], s4 = a1[4] + bv[4];
            const float si = 1.f / (1.f + expf(-s0));
            const float sl = 1.f / (1.f + expf(-s1));
            const float sr = 1.f / (1.f + expf(-s2));
            const float so = 1.f / (1.f + expf(-s3));
            const float c_red = sl * cl + sr * cr + si * tanhf(s4);
            const float h_red = so * tanhf(c_red);
            cstk[(cw[frow] * NROW + frow) * NHID + colq] = c_red;
            const unsigned long long pv =
                ((unsigned long long)nbar << 32) | (unsigned long long)__float_as_uint(h_red);
            __hip_atomic_store(p64 + d_wr[frow] + gn, pv,
                               __ATOMIC_RELAXED, __HIP_MEMORY_SCOPE_AGENT);
        }
        // no trailing barrier: next iteration's controller sync re-converges
    }

    // ---- output: epoch-poll final stack tops ----
    if (tid < NROW) {
        const int top = min(max(ptr - 1, 0), SLOTS - 1);
        const short tt = tg[tid][top];
        const int grow = rbase + tid;
        if (tt >= 0)       { d_oh[tid] = (unsigned)((grow * LSEQ + (int)tt) * PROJW); e_oh[tid] = 0; }
        else if (tt <= -3) { d_oh[tid] = SENT; e_oh[tid] = 0; }
        else { const int par = (tt == -2);
               d_oh[tid] = NODEBIT | (unsigned)(PAIRB + ((par * BSZ + grow) * SLOTS + top) * HDIM);
               e_oh[tid] = eps[tid][top]; }
    }
    __syncthreads();
    if (tid < 64) {
        const int orow = tid >> 3;
        const int ocol = n0 + (tid & 7);
        const unsigned oh = d_oh[orow];
        float v;
        if (oh == SENT) v = 0.f;
        else if (!(oh & NODEBIT)) v = ws[oh + ocol];
        else {
            const unsigned pb = (oh & ~NODEBIT) + ocol;
            const unsigned ee = e_oh[orow];
            unsigned long long pv;
            for (;;) {
                pv = __hip_atomic_load(p64 + pb, __ATOMIC_RELAXED, __HIP_MEMORY_SCOPE_AGENT);
                if ((unsigned)(pv >> 32) >= ee) break;
                __builtin_amdgcn_s_sleep(1);
            }
            v = __uint_as_float((unsigned)pv);
        }
        out[(size_t)(rbase + orow) * HDIM + ocol] = v;
    }
}

// ---------------- Host launch ----------------
extern "C" void kernel_launch(void* const* d_in, const int* in_sizes, int n_in,
                              void* d_out, int out_size, void* d_ws, size_t ws_size,
                              hipStream_t stream) {
    const float* sentence    = (const float*)d_in[0];
    const int*   transitions = (const int*)  d_in[1];
    const float* W_word      = (const float*)d_in[2];
    const float* b_word      = (const float*)d_in[3];
    const float* W_left      = (const float*)d_in[4];
    const float* W_right     = (const float*)d_in[5];
    const float* b_reduce    = (const float*)d_in[6];
    float* out  = (float*)d_out;
    float* ws_f = (float*)d_ws;

    // ws (dwords): [proj 16.78M][(h,epoch) pairs 512 KB]
    // epochs must be cleared every launch (graph replays reuse ws)
    hipMemsetAsync((char*)d_ws + (size_t)STACKF * 4, 0,
                   (size_t)PAIR_CNT * 8, stream);

    dim3 g1(PROJW / 64, (BSZ * LSEQ) / 64);
    proj_gemm<<<g1, 256, 0, stream>>>(sentence, W_word, b_word, ws_f);

    scan_coop<<<NBLK, 256, 0, stream>>>(transitions, W_left, W_right, b_reduce,
                                        ws_f, out);
}

// Round 10
// 3058.624 us; speedup vs baseline: 1.1206x; 1.1206x over previous
//
#include <hip/hip_runtime.h>
#include <hip/hip_bf16.h>
#include <math.h>

#define BSZ   64
#define LSEQ  512
#define EDIM  300
#define HDIM  256
#define TLEN  1023
#define PROJW 512
#define GW    1280

#define NROW  8         // rows per block (row-group)
#define NHID  8         // gate-columns per block
#define NRG   8
#define NBLK  256
#define SLOTS 2

#define PROJ_N   (BSZ*LSEQ*PROJW)          // 16,777,216 dwords
#define STACKF   PROJ_N                    // pair region base (dwords)
#define PAIRB    (STACKF/2)                // pair region base (8B pair units)
#define PAIR_CNT (2*BSZ*SLOTS*HDIM)        // 65,536 pairs = 512 KB

#define NODEBIT 0x80000000u
#define SENT    0xFFFFFFFFu
#define LROW    264                        // LDS row stride (dwords)
#define HRO     (NROW*LROW + 4)            // hr-buffer offset
#define RPITCH  328                        // red per-group stride (dwords)
#define RROW    41                         // red per-row stride

// ---------------- Kernel 1: proj = sentence @ W_word + b_word ----------------
__global__ void __launch_bounds__(256)
proj_gemm(const float* __restrict__ A, const float* __restrict__ W,
          const float* __restrict__ bias, float* __restrict__ out) {
    __shared__ float As[8][65];
    __shared__ float Bs[8][64];
    const int tid = threadIdx.x;
    const int tx = tid & 15, ty = tid >> 4;
    const int bm = blockIdx.y, bn = blockIdx.x;

    float acc[4][4] = {};
    const int e  = tid * 2;
    const int ar = e >> 3, ac = e & 7;
    const int br = e >> 6, bc = e & 63;

    for (int k0 = 0; k0 < EDIM; k0 += 8) {
        __syncthreads();
        {
            const float* Ap = A + (size_t)(bm * 64 + ar) * EDIM;
            int gk = k0 + ac;
            As[ac][ar]     = (gk     < EDIM) ? Ap[gk]     : 0.f;
            As[ac + 1][ar] = (gk + 1 < EDIM) ? Ap[gk + 1] : 0.f;
            int gkb = k0 + br;
            float w0 = 0.f, w1 = 0.f;
            if (gkb < EDIM) {
                const float* Wp = W + (size_t)gkb * PROJW + bn * 64;
                w0 = Wp[bc]; w1 = Wp[bc + 1];
            }
            Bs[br][bc] = w0; Bs[br][bc + 1] = w1;
        }
        __syncthreads();
        #pragma unroll
        for (int kk = 0; kk < 8; ++kk) {
            float a[4], b[4];
            #pragma unroll
            for (int i = 0; i < 4; ++i) a[i] = As[kk][ty * 4 + i];
            #pragma unroll
            for (int j = 0; j < 4; ++j) b[j] = Bs[kk][tx * 4 + j];
            #pragma unroll
            for (int i = 0; i < 4; ++i)
                #pragma unroll
                for (int j = 0; j < 4; ++j)
                    acc[i][j] += a[i] * b[j];
        }
    }
    #pragma unroll
    for (int i = 0; i < 4; ++i) {
        const int row  = bm * 64 + ty * 4 + i;
        const int col0 = bn * 64 + tx * 4;
        float* op = out + (size_t)row * PROJW + col0;
        #pragma unroll
        for (int j = 0; j < 4; ++j) op[j] = acc[i][j] + bias[col0 + j];
    }
}

// ------------- helpers -------------------------------------------------------
__device__ __forceinline__ int qswz(int Q, int row) {
    return Q ^ row ^ ((Q >> 3) & 7);
}

__device__ __forceinline__ unsigned long long pld(const unsigned long long* p) {
    return __hip_atomic_load(p, __ATOMIC_RELAXED, __HIP_MEMORY_SCOPE_AGENT);
}

// cheap-spin octet fetch: spin on ONE pair (1 LLC load/iter), then batch-load
// all 8 pairs and verify the epochs that travel atomically with each value.
__device__ __forceinline__ void fetch_octet(const unsigned long long* pb,
                                            unsigned ee, float* h) {
    while ((unsigned)(pld(pb) >> 32) < ee)
        __builtin_amdgcn_s_sleep(1);
    for (;;) {
        unsigned long long v[8];
        #pragma unroll
        for (int i = 0; i < 8; ++i) v[i] = pld(pb + i);
        bool ok = true;
        #pragma unroll
        for (int i = 0; i < 8; ++i) ok &= ((unsigned)(v[i] >> 32) >= ee);
        if (ok) {
            #pragma unroll
            for (int i = 0; i < 8; ++i) h[i] = __uint_as_float((unsigned)v[i]);
            return;
        }
        __builtin_amdgcn_s_sleep(1);
    }
}

// ------------- Kernel 2: cooperative scan, epoch dataflow, cheap spin --------
__global__ void __launch_bounds__(256, 1)
scan_coop(const int* __restrict__ trans,
          const float* __restrict__ Wl, const float* __restrict__ Wr,
          const float* __restrict__ bred,
          float* __restrict__ ws, float* __restrict__ out) {
    __shared__ __align__(16) float hbuf[HRO + NROW * LROW];   // hl | pad | hr
    __shared__ __align__(16) float red[16 * RPITCH];          // k-split partials
    __shared__ float    cstk[2 * SLOTS * NROW * NHID];        // private cell stack
    __shared__ unsigned tbits[NROW][32];
    __shared__ unsigned fbits[32];
    __shared__ short    tg[NROW][SLOTS];
    __shared__ unsigned eps[NROW][SLOTS];
    __shared__ unsigned d_hl[NROW], d_hr[NROW], d_wr[NROW];
    __shared__ unsigned e_hl[NROW], e_hr[NROW];
    __shared__ unsigned c_l[NROW], c_r[NROW], cw[NROW];
    __shared__ unsigned d_oh[NROW], e_oh[NROW];
    __shared__ int      isred[NROW];

    const int tid   = threadIdx.x;
    // XCD-local mapping (performance heuristic ONLY; correctness is
    // agent-scope atomics — no XCD assumption):
    const int rg    = blockIdx.x & 7;      // row-group
    const int cs    = blockIdx.x >> 3;     // col-slice
    const int rbase = rg * NROW;
    const int n0    = cs * NHID;

    const int srow = tid >> 5, sc = tid & 31;   // staging map
    const int colq = tid & 7;                   // gemm: gate-col
    const int rh   = (tid >> 3) & 1;            // gemm: row half
    const int m    = (tid >> 4) & 1;            // gemm: matrix (0=hl, 1=hr)
    const int w8   = tid >> 5;                  // gemm: k-group
    const int gn   = n0 + colq;
    const int orow = tid >> 3;                  // finalize row (tid<64)

    unsigned long long* p64 = (unsigned long long*)ws;

    // ---- weight slice into REGISTERS (once) ----
    float4 w[8][5];
    {
        const float* src = (m == 0) ? Wl : Wr;
        const int kbase = w8 * 32;
        #pragma unroll
        for (int j = 0; j < 8; ++j) {
            const int k0 = kbase + j * 4;
            #pragma unroll
            for (int g = 0; g < 5; ++g) {
                w[j][g].x = src[(size_t)(k0 + 0) * GW + g * HDIM + gn];
                w[j][g].y = src[(size_t)(k0 + 1) * GW + g * HDIM + gn];
                w[j][g].z = src[(size_t)(k0 + 2) * GW + g * HDIM + gn];
                w[j][g].w = src[(size_t)(k0 + 3) * GW + g * HDIM + gn];
            }
        }
    }
    #pragma unroll
    for (int j = 0; j < 8; ++j)
        #pragma unroll
        for (int g = 0; g < 5; ++g)
            asm volatile("" : "+v"(w[j][g].x), "+v"(w[j][g].y),
                              "+v"(w[j][g].z), "+v"(w[j][g].w));

    // ---- transition bitmasks (shift=1) ----
    if (tid < NROW * 32) {
        const int r2 = tid >> 5, wd = tid & 31;
        unsigned bits = 0;
        for (int j = 0; j < 32; ++j) {
            const int t = wd * 32 + j;
            if (t < TLEN && trans[(size_t)(rbase + r2) * TLEN + t] == 3) bits |= (1u << j);
        }
        tbits[r2][wd] = bits;
    }
    if (tid < NROW) {
        tg[tid][0] = -3; tg[tid][1] = -3;
        eps[tid][0] = 0; eps[tid][1] = 0;
        isred[tid] = 0;
    }
    __syncthreads();
    if (tid < 32) {   // rg-local "any reduce at step t" bits
        unsigned fb = 0;
        #pragma unroll
        for (int r2 = 0; r2 < NROW; ++r2) fb |= ~tbits[r2][tid];
        if (tid == 31) fb &= 0x7FFFFFFFu;   // t=1023 invalid
        fbits[tid] = fb;
    }

    float bv[5];
    #pragma unroll
    for (int g = 0; g < 5; ++g) bv[g] = bred[g * HDIM + gn];

    int ptr = 0, bp = 0;       // controller state (thread tid<NROW owns row tid)
    unsigned nbar = 0;
    __syncthreads();

    for (int t = 0; t < TLEN; ++t) {
        const int redstep = (fbits[t >> 5] >> (t & 31)) & 1;
        if (redstep) ++nbar;

        if (tid < NROW) {
            const int r = tid, grow = rbase + r;
            const int is_shift = (tbits[r][t >> 5] >> (t & 31)) & 1;
            if (is_shift) {
                int pos = ptr; if (pos < 0) pos = 0; if (pos > SLOTS - 1) pos = SLOTS - 1;
                tg[r][pos] = (short)min(bp, LSEQ - 1);
                ptr++; bp++;
                isred[r] = 0;
            } else {
                const int i1 = min(max(ptr - 1, 0), SLOTS - 1);
                const int i2 = min(max(ptr - 2, 0), SLOTS - 1);
                const short t1 = tg[r][i1], t2 = tg[r][i2];
                unsigned dl, el = 0, cdl;
                if (t2 >= 0)       { dl = (unsigned)((grow * LSEQ + (int)t2) * PROJW); cdl = dl + HDIM; }
                else if (t2 <= -3) { dl = SENT; cdl = SENT; }
                else { const int par = (t2 == -2);
                       dl = NODEBIT | (unsigned)(PAIRB + ((par * BSZ + grow) * SLOTS + i2) * HDIM);
                       el = eps[r][i2];
                       cdl = NODEBIT | (unsigned)(par * 2 + i2); }
                unsigned dr, er = 0, cdr;
                if (t1 >= 0)       { dr = (unsigned)((grow * LSEQ + (int)t1) * PROJW); cdr = dr + HDIM; }
                else if (t1 <= -3) { dr = SENT; cdr = SENT; }
                else { const int par = (t1 == -2);
                       dr = NODEBIT | (unsigned)(PAIRB + ((par * BSZ + grow) * SLOTS + i1) * HDIM);
                       er = eps[r][i1];
                       cdr = NODEBIT | (unsigned)(par * 2 + i1); }
                d_hl[r] = dl; e_hl[r] = el; c_l[r] = cdl;
                d_hr[r] = dr; e_hr[r] = er; c_r[r] = cdr;
                const int pnew = (t2 == -1) ? 1 : 0;
                d_wr[r] = (unsigned)(PAIRB + ((pnew * BSZ + grow) * SLOTS + i2) * HDIM);
                cw[r]   = (unsigned)(pnew * 2 + i2);
                eps[r][i2] = nbar;
                tg[r][i2] = (short)(pnew ? -2 : -1);
                ptr--;
                isred[r] = 1;
            }
        }
        __syncthreads();

        if (!redstep) continue;

        // ---- word-path c prefetch for finalize lanes (issue early, use late) ----
        float clw = 0.f, crw = 0.f;
        if (tid < 64 && isred[orow]) {
            const unsigned cdl = c_l[orow], cdr = c_r[orow];
            if (cdl != SENT && !(cdl & NODEBIT)) clw = ws[cdl + gn];
            if (cdr != SENT && !(cdr & NODEBIT)) crw = ws[cdr + gn];
        }

        // ---- staging: word loads first (cached), node octets via cheap spin ----
        if (isred[srow]) {
            const unsigned oh0 = d_hl[srow], oh1 = d_hr[srow];
            const bool nd0 = (oh0 != SENT) && (oh0 & NODEBIT);
            const bool nd1 = (oh1 != SENT) && (oh1 & NODEBIT);
            float h0[8], h1[8];

            if (oh0 == SENT) {
                #pragma unroll
                for (int i = 0; i < 8; ++i) h0[i] = 0.f;
            } else if (!nd0) {
                const float4 a = *(const float4*)(ws + oh0 + sc * 8);
                const float4 b = *(const float4*)(ws + oh0 + sc * 8 + 4);
                h0[0]=a.x; h0[1]=a.y; h0[2]=a.z; h0[3]=a.w;
                h0[4]=b.x; h0[5]=b.y; h0[6]=b.z; h0[7]=b.w;
            }
            if (oh1 == SENT) {
                #pragma unroll
                for (int i = 0; i < 8; ++i) h1[i] = 0.f;
            } else if (!nd1) {
                const float4 a = *(const float4*)(ws + oh1 + sc * 8);
                const float4 b = *(const float4*)(ws + oh1 + sc * 8 + 4);
                h1[0]=a.x; h1[1]=a.y; h1[2]=a.z; h1[3]=a.w;
                h1[4]=b.x; h1[5]=b.y; h1[6]=b.z; h1[7]=b.w;
            }
            if (nd0) fetch_octet(p64 + (oh0 & ~NODEBIT) + sc * 8, e_hl[srow], h0);
            if (nd1) fetch_octet(p64 + (oh1 & ~NODEBIT) + sc * 8, e_hr[srow], h1);

            // LDS writes (swizzled quads)
            *(float4*)&hbuf[srow * LROW + 4 * qswz(2 * sc + 0, srow)] =
                make_float4(h0[0], h0[1], h0[2], h0[3]);
            *(float4*)&hbuf[srow * LROW + 4 * qswz(2 * sc + 1, srow)] =
                make_float4(h0[4], h0[5], h0[6], h0[7]);
            *(float4*)&hbuf[HRO + srow * LROW + 4 * qswz(2 * sc + 0, srow)] =
                make_float4(h1[0], h1[1], h1[2], h1[3]);
            *(float4*)&hbuf[HRO + srow * LROW + 4 * qswz(2 * sc + 1, srow)] =
                make_float4(h1[4], h1[5], h1[6], h1[7]);
        }
        __syncthreads();

        // ---- GEMM: register weights; thread = (colq, rh, m, w8) ----
        float acc[4][5];
        #pragma unroll
        for (int r = 0; r < 4; ++r)
            #pragma unroll
            for (int g = 0; g < 5; ++g) acc[r][g] = 0.f;
        {
            const float* hb = hbuf + m * HRO;
            #pragma unroll
            for (int j = 0; j < 8; ++j) {
                const int kq = w8 * 8 + j;
                #pragma unroll
                for (int r = 0; r < 4; ++r) {
                    const int row = rh * 4 + r;
                    const float4 x = *(const float4*)&hb[row * LROW + 4 * qswz(kq, row)];
                    #pragma unroll
                    for (int g = 0; g < 5; ++g)
                        acc[r][g] += x.x * w[j][g].x + x.y * w[j][g].y
                                   + x.z * w[j][g].z + x.w * w[j][g].w;
                }
            }
        }
        {
            const int g16 = w8 * 2 + m;
            #pragma unroll
            for (int r = 0; r < 4; ++r) {
                const int row = rh * 4 + r;
                #pragma unroll
                for (int g = 0; g < 5; ++g)
                    red[g16 * RPITCH + row * RROW + colq * 5 + g] = acc[r][g];
            }
        }
        __syncthreads();

        // ---- finalize: wave 0 only; store (h, epoch) pair, c stays local ----
        if (tid < 64) {
            if (isred[orow]) {
                float s[5];
                #pragma unroll
                for (int g = 0; g < 5; ++g) s[g] = bv[g];
                #pragma unroll
                for (int q = 0; q < 16; ++q)
                    #pragma unroll
                    for (int g = 0; g < 5; ++g)
                        s[g] += red[q * RPITCH + orow * RROW + colq * 5 + g];
                const unsigned cdl = c_l[orow], cdr = c_r[orow];
                const float cl = (cdl == SENT) ? 0.f :
                    ((cdl & NODEBIT) ? cstk[((cdl & 3) * NROW + orow) * NHID + colq] : clw);
                const float cr = (cdr == SENT) ? 0.f :
                    ((cdr & NODEBIT) ? cstk[((cdr & 3) * NROW + orow) * NHID + colq] : crw);
                const float si = 1.f / (1.f + expf(-s[0]));
                const float sl = 1.f / (1.f + expf(-s[1]));
                const float sr = 1.f / (1.f + expf(-s[2]));
                const float so = 1.f / (1.f + expf(-s[3]));
                const float c_red = sl * cl + sr * cr + si * tanhf(s[4]);
                const float h_red = so * tanhf(c_red);
                cstk[(cw[orow] * NROW + orow) * NHID + colq] = c_red;
                const unsigned long long pv =
                    ((unsigned long long)nbar << 32) | (unsigned long long)__float_as_uint(h_red);
                __hip_atomic_store(p64 + d_wr[orow] + gn, pv,
                                   __ATOMIC_RELAXED, __HIP_MEMORY_SCOPE_AGENT);
            }
        }
        // no trailing barrier: epoch-tagged data IS the synchronization
    }

    // ---- output: epoch-poll final stack tops ----
    if (tid < NROW) {
        const int top = min(max(ptr - 1, 0), SLOTS - 1);
        const short tt = tg[tid][top];
        const int grow = rbase + tid;
        if (tt >= 0)       { d_oh[tid] = (unsigned)((grow * LSEQ + (int)tt) * PROJW); e_oh[tid] = 0; }
        else if (tt <= -3) { d_oh[tid] = SENT; e_oh[tid] = 0; }
        else { const int par = (tt == -2);
               d_oh[tid] = NODEBIT | (unsigned)(PAIRB + ((par * BSZ + grow) * SLOTS + top) * HDIM);
               e_oh[tid] = eps[tid][top]; }
    }
    __syncthreads();
    if (tid < 64) {
        const int ocol = n0 + (tid & 7);
        const unsigned oh = d_oh[orow];
        float v;
        if (oh == SENT) v = 0.f;
        else if (!(oh & NODEBIT)) v = ws[oh + ocol];
        else {
            const unsigned long long* pb = p64 + (oh & ~NODEBIT) + ocol;
            const unsigned ee = e_oh[orow];
            unsigned long long pv;
            for (;;) {
                pv = pld(pb);
                if ((unsigned)(pv >> 32) >= ee) break;
                __builtin_amdgcn_s_sleep(1);
            }
            v = __uint_as_float((unsigned)pv);
        }
        out[(size_t)(rbase + orow) * HDIM + ocol] = v;
    }
}

// ---------------- Host launch ----------------
extern "C" void kernel_launch(void* const* d_in, const int* in_sizes, int n_in,
                              void* d_out, int out_size, void* d_ws, size_t ws_size,
                              hipStream_t stream) {
    const float* sentence    = (const float*)d_in[0];
    const int*   transitions = (const int*)  d_in[1];
    const float* W_word      = (const float*)d_in[2];
    const float* b_word      = (const float*)d_in[3];
    const float* W_left      = (const float*)d_in[4];
    const float* W_right     = (const float*)d_in[5];
    const float* b_reduce    = (const float*)d_in[6];
    float* out  = (float*)d_out;
    float* ws_f = (float*)d_ws;

    // ws (dwords): [proj 16.78M][(h,epoch) pairs 512 KB]
    // epochs must be cleared every launch (graph replays reuse ws)
    hipMemsetAsync((char*)d_ws + (size_t)STACKF * 4, 0,
                   (size_t)PAIR_CNT * 8, stream);

    dim3 g1(PROJW / 64, (BSZ * LSEQ) / 64);
    proj_gemm<<<g1, 256, 0, stream>>>(sentence, W_word, b_word, ws_f);

    scan_coop<<<NBLK, 256, 0, stream>>>(transitions, W_left, W_right, b_reduce,
                                        ws_f, out);
}